// Round 1
// baseline (1897.207 us; speedup 1.0000x reference)
//
#include <hip/hip_runtime.h>
#include <hip/hip_bf16.h>

typedef short s16x8 __attribute__((ext_vector_type(8)));
typedef float f32x4 __attribute__((ext_vector_type(4)));

#define DEVI __device__ __forceinline__

DEVI unsigned short f2bf(float f) {
  unsigned u = __builtin_bit_cast(unsigned, f);
  u += 0x7FFFu + ((u >> 16) & 1u);
  return (unsigned short)(u >> 16);
}
DEVI float bf2f(unsigned short h) {
  unsigned u = ((unsigned)h) << 16;
  return __builtin_bit_cast(float, u);
}

DEVI void gload_lds16(const void* g, void* l) {
  __builtin_amdgcn_global_load_lds((const __attribute__((address_space(1))) void*)g,
                                   (__attribute__((address_space(3))) void*)l, 16, 0, 0);
}

// ---------------- fp32 -> bf16 conversion ----------------
__global__ void cvt_f2b(const float* __restrict__ src, unsigned short* __restrict__ dst, int n4) {
  int i = blockIdx.x * blockDim.x + threadIdx.x;
  if (i < n4) {
    float4 v = ((const float4*)src)[i];
    ushort4 o;
    o.x = f2bf(v.x); o.y = f2bf(v.y); o.z = f2bf(v.z); o.w = f2bf(v.w);
    ((ushort4*)dst)[i] = o;
  }
}

// ---------------- bf16 MFMA GEMM: C = A @ B^T ----------------
// A: (M,K) bf16 row-major, B: (Nmat,K) bf16 row-major.
// MODE 0: scatter qkv into q/k/v buffers laid out (B*H, Ntok, 96) bf16.
// MODE 1: C += bias, write fp32 row-major to Cout.
template <int MODE>
__global__ __launch_bounds__(256) void gemm_bf16(
    const unsigned short* __restrict__ A, const unsigned short* __restrict__ B,
    int M, int Nmat, int K, int Ntok,
    unsigned short* __restrict__ Oq, unsigned short* __restrict__ Ok, unsigned short* __restrict__ Ov,
    const float* __restrict__ bias, float* __restrict__ Cout) {
  __shared__ unsigned short As[128 * 32];
  __shared__ unsigned short Bs[128 * 32];
  const int tid = threadIdx.x;
  const int wave = tid >> 6, lane = tid & 63;
  const int tm = blockIdx.x, tn = blockIdx.y;
  const int wr = wave >> 1, wc = wave & 1;
  const int sr = lane >> 2;          // 0..15
  const int sc = (lane & 3) * 8;     // 0,8,16,24
  const int l15 = lane & 15, lg = lane >> 4;
  f32x4 acc[4][4] = {};

  for (int kt = 0; kt < K; kt += 32) {
    #pragma unroll
    for (int i = 0; i < 2; ++i) {
      int r = wave * 32 + i * 16 + sr;
      long ar = (long)tm * 128 + r; if (ar >= M) ar = M - 1;
      long br = (long)tn * 128 + r; if (br >= Nmat) br = Nmat - 1;
      gload_lds16(A + ar * K + kt + sc, &As[(wave * 32 + i * 16) * 32]);
      gload_lds16(B + br * K + kt + sc, &Bs[(wave * 32 + i * 16) * 32]);
    }
    asm volatile("s_waitcnt vmcnt(0)" ::: "memory");
    __syncthreads();
    s16x8 a[4], bfr[4];
    #pragma unroll
    for (int m = 0; m < 4; ++m)
      a[m] = *(const s16x8*)&As[(wr * 64 + m * 16 + l15) * 32 + lg * 8];
    #pragma unroll
    for (int n = 0; n < 4; ++n)
      bfr[n] = *(const s16x8*)&Bs[(wc * 64 + n * 16 + l15) * 32 + lg * 8];
    #pragma unroll
    for (int m = 0; m < 4; ++m)
      #pragma unroll
      for (int n = 0; n < 4; ++n)
        acc[m][n] = __builtin_amdgcn_mfma_f32_16x16x32_bf16(a[m], bfr[n], acc[m][n], 0, 0, 0);
    __syncthreads();
  }

  const long rbase = (long)tm * 128 + wr * 64 + lg * 4;
  const int cbase = tn * 128 + wc * 64 + l15;
  #pragma unroll
  for (int m = 0; m < 4; ++m)
    #pragma unroll
    for (int n = 0; n < 4; ++n)
      #pragma unroll
      for (int reg = 0; reg < 4; ++reg) {
        long gr = rbase + m * 16 + reg;
        int gc = cbase + n * 16;
        if (gr < M) {
          float c = acc[m][n][reg];
          if (MODE == 0) {
            int which = gc / 768; int rem = gc - which * 768;
            int head = rem / 96;  int d = rem - head * 96;
            int b = (int)(gr / Ntok); int tok = (int)(gr - (long)b * Ntok);
            unsigned short* dst = (which == 0) ? Oq : (which == 1) ? Ok : Ov;
            dst[((long)(b * 8 + head) * Ntok + tok) * 96 + d] = f2bf(c);
          } else {
            Cout[gr * (long)Nmat + gc] = c + bias[gc];
          }
        }
      }
}

// ---------------- depthwise 3x3x3 pool (stride 1,2,2) + LayerNorm ----------------
// src: (64 pairs, 6273, 96) bf16. dst: (64, 1569, 96). Row 0 = cls (no conv).
__global__ __launch_bounds__(384) void pool_ln(
    const unsigned short* __restrict__ src, const float* __restrict__ cw,
    const float* __restrict__ lw, const float* __restrict__ lb,
    unsigned short* __restrict__ dstb, float* __restrict__ dstf) {
  const int c = threadIdx.x;   // 0..95
  const int r = threadIdx.y;   // 0..3
  const int pair = blockIdx.y;
  const int p = blockIdx.x * 4 + r;
  __shared__ float red[4][128][2];
  float val = 0.f;
  const bool active = (p < 1569);
  if (active) {
    if (p == 0) {
      val = bf2f(src[((long)pair * 6273) * 96 + c]);
    } else {
      const int q = p - 1;
      const int tp = q / 196, rem = q - tp * 196;
      const int hp = rem / 14, wp = rem - hp * 14;
      const float* w = cw + c * 27;
      float s = 0.f;
      #pragma unroll
      for (int dt = 0; dt < 3; ++dt) {
        int t = tp + dt - 1;
        if (t < 0 || t >= 8) continue;
        #pragma unroll
        for (int dh = 0; dh < 3; ++dh) {
          int hh = hp * 2 + dh - 1;
          if (hh < 0 || hh >= 28) continue;
          #pragma unroll
          for (int dw = 0; dw < 3; ++dw) {
            int ww = wp * 2 + dw - 1;
            if (ww < 0 || ww >= 28) continue;
            s += bf2f(src[((long)pair * 6273 + 1 + (t * 28 + hh) * 28 + ww) * 96 + c]) * w[dt * 9 + dh * 3 + dw];
          }
        }
      }
      val = s;
    }
  }
  red[r][c][0] = active ? val : 0.f;
  red[r][c][1] = active ? val * val : 0.f;
  if (c < 32) { red[r][96 + c][0] = 0.f; red[r][96 + c][1] = 0.f; }
  __syncthreads();
  for (int s2 = 64; s2 > 0; s2 >>= 1) {
    if (c < s2) {
      red[r][c][0] += red[r][c + s2][0];
      red[r][c][1] += red[r][c + s2][1];
    }
    __syncthreads();
  }
  if (active) {
    const float mean = red[r][0][0] * (1.f / 96.f);
    const float var = red[r][0][1] * (1.f / 96.f) - mean * mean;
    const float nv = (val - mean) * rsqrtf(var + 1e-5f) * lw[c] + lb[c];
    const long o = ((long)pair * 1569 + p) * 96 + c;
    dstb[o] = f2bf(nv);
    if (dstf) dstf[o] = nv;
  }
}

// ---------------- flash attention + residual ----------------
// Q/K/V: (64, 1569, 96) bf16; Qf: fp32 q (residual); Out: (8,1569,768) bf16.
__global__ __launch_bounds__(256) void flash_attn(
    const unsigned short* __restrict__ Qb, const unsigned short* __restrict__ Kb,
    const unsigned short* __restrict__ Vb, const float* __restrict__ Qf,
    unsigned short* __restrict__ Out) {
  const int Np = 1569;
  const int pair = blockIdx.y;
  const int b = pair >> 3, h = pair & 7;
  const int tid = threadIdx.x, wave = tid >> 6, lane = tid & 63;
  const int l15 = lane & 15, lg = lane >> 4;
  const int qbase = blockIdx.x * 64 + wave * 16;
  __shared__ unsigned short Ks[32][104];   // keys row-major, padded pitch
  __shared__ unsigned short Vt[96][40];    // V transposed: [d][key], padded pitch
  __shared__ unsigned short Ps[4][16][40]; // per-wave P round-trip

  s16x8 qf[3];
  {
    int qr = qbase + l15; if (qr >= Np) qr = Np - 1;
    const unsigned short* qp = &Qb[((long)pair * Np + qr) * 96];
    qf[0] = *(const s16x8*)(qp + 0  + lg * 8);
    qf[1] = *(const s16x8*)(qp + 32 + lg * 8);
    qf[2] = *(const s16x8*)(qp + 64 + lg * 8);
  }
  f32x4 accO[6] = {};
  float mrun[4], lrun[4];
  #pragma unroll
  for (int i = 0; i < 4; ++i) { mrun[i] = -1e30f; lrun[i] = 0.f; }

  const float scale = 0.1020620726159658f; // 96^-0.5
  const int NT = (Np + 31) / 32;
  for (int kt = 0; kt < NT; ++kt) {
    __syncthreads();
    for (int cc = tid; cc < 384; cc += 256) {
      int key = cc / 12, dp = (cc - key * 12) * 8;
      int gk = kt * 32 + key;
      s16x8 kv = {0,0,0,0,0,0,0,0}, vv = {0,0,0,0,0,0,0,0};
      if (gk < Np) {
        kv = *(const s16x8*)&Kb[((long)pair * Np + gk) * 96 + dp];
        vv = *(const s16x8*)&Vb[((long)pair * Np + gk) * 96 + dp];
      }
      *(s16x8*)&Ks[key][dp] = kv;
      #pragma unroll
      for (int j = 0; j < 8; ++j) Vt[dp + j][key] = (unsigned short)vv[j];
    }
    __syncthreads();

    f32x4 s0 = {}, s1 = {};
    #pragma unroll
    for (int kk = 0; kk < 3; ++kk) {
      s16x8 b0 = *(const s16x8*)&Ks[l15][kk * 32 + lg * 8];
      s16x8 b1 = *(const s16x8*)&Ks[16 + l15][kk * 32 + lg * 8];
      s0 = __builtin_amdgcn_mfma_f32_16x16x32_bf16(qf[kk], b0, s0, 0, 0, 0);
      s1 = __builtin_amdgcn_mfma_f32_16x16x32_bf16(qf[kk], b1, s1, 0, 0, 0);
    }

    const bool v0 = (kt * 32 + l15) < Np;
    const bool v1 = (kt * 32 + 16 + l15) < Np;
    float sf[4];
    #pragma unroll
    for (int i2 = 0; i2 < 4; ++i2) {
      float sm0 = v0 ? s0[i2] * scale : -1e30f;
      float sm1 = v1 ? s1[i2] * scale : -1e30f;
      float t = fmaxf(sm0, sm1);
      t = fmaxf(t, __shfl_xor(t, 1, 16));
      t = fmaxf(t, __shfl_xor(t, 2, 16));
      t = fmaxf(t, __shfl_xor(t, 4, 16));
      t = fmaxf(t, __shfl_xor(t, 8, 16));
      float mnew = fmaxf(mrun[i2], t);
      sf[i2] = __expf(mrun[i2] - mnew);
      mrun[i2] = mnew;
      float p0 = __expf(sm0 - mnew);
      float p1 = __expf(sm1 - mnew);
      float ps = p0 + p1;
      ps += __shfl_xor(ps, 1, 16);
      ps += __shfl_xor(ps, 2, 16);
      ps += __shfl_xor(ps, 4, 16);
      ps += __shfl_xor(ps, 8, 16);
      lrun[i2] = lrun[i2] * sf[i2] + ps;
      Ps[wave][lg * 4 + i2][l15] = f2bf(p0);
      Ps[wave][lg * 4 + i2][16 + l15] = f2bf(p1);
    }
    #pragma unroll
    for (int db = 0; db < 6; ++db)
      #pragma unroll
      for (int i2 = 0; i2 < 4; ++i2)
        accO[db][i2] *= sf[i2];
    asm volatile("s_waitcnt lgkmcnt(0)" ::: "memory");
    __builtin_amdgcn_sched_barrier(0);
    s16x8 ap = *(const s16x8*)&Ps[wave][l15][lg * 8];
    #pragma unroll
    for (int db = 0; db < 6; ++db) {
      s16x8 bv = *(const s16x8*)&Vt[db * 16 + l15][lg * 8];
      accO[db] = __builtin_amdgcn_mfma_f32_16x16x32_bf16(ap, bv, accO[db], 0, 0, 0);
    }
  }

  #pragma unroll
  for (int i2 = 0; i2 < 4; ++i2) lrun[i2] = 1.f / lrun[i2];
  const int q0 = qbase + lg * 4;
  #pragma unroll
  for (int db = 0; db < 6; ++db) {
    int d = db * 16 + l15;
    #pragma unroll
    for (int i2 = 0; i2 < 4; ++i2) {
      int q = q0 + i2;
      if (q < Np) {
        float o = accO[db][i2] * lrun[i2] + Qf[((long)pair * Np + q) * 96 + d];
        Out[((long)b * Np + q) * 768 + h * 96 + d] = f2bf(o);
      }
    }
  }
}

extern "C" void kernel_launch(void* const* d_in, const int* in_sizes, int n_in,
                              void* d_out, int out_size, void* d_ws, size_t ws_size,
                              hipStream_t stream) {
  const float* x     = (const float*)d_in[0];
  const float* qkv_w = (const float*)d_in[1];
  const float* pqw   = (const float*)d_in[2];
  const float* pkw   = (const float*)d_in[3];
  const float* pvw   = (const float*)d_in[4];
  const float* nqw   = (const float*)d_in[5];
  const float* nqb   = (const float*)d_in[6];
  const float* nkw   = (const float*)d_in[7];
  const float* nkb   = (const float*)d_in[8];
  const float* nvw   = (const float*)d_in[9];
  const float* nvb   = (const float*)d_in[10];
  const float* pw    = (const float*)d_in[11];
  const float* pb    = (const float*)d_in[12];

  const int Ntok = 6273, DIM = 768, Np = 1569;
  const long Mq = 8L * Ntok;  // 50184
  const long Mp = 8L * Np;    // 12552

  char* w = (char*)d_ws;
  unsigned short* xb  = (unsigned short*)w; w += Mq * DIM * 2;
  unsigned short* wb  = (unsigned short*)w; w += 3L * DIM * DIM * 2;
  unsigned short* pwb = (unsigned short*)w; w += (long)DIM * DIM * 2;
  unsigned short* qb  = (unsigned short*)w; w += 64L * Ntok * 96 * 2;
  unsigned short* kb  = (unsigned short*)w; w += 64L * Ntok * 96 * 2;
  unsigned short* vb  = (unsigned short*)w; w += 64L * Ntok * 96 * 2;
  unsigned short* qpb = (unsigned short*)w; w += 64L * Np * 96 * 2;
  unsigned short* kpb = (unsigned short*)w; w += 64L * Np * 96 * 2;
  unsigned short* vpb = (unsigned short*)w; w += 64L * Np * 96 * 2;
  float*          qpf = (float*)w;          w += 64L * Np * 96 * 4;
  unsigned short* ares= (unsigned short*)w; w += Mp * DIM * 2;

  {
    int n4 = (int)(Mq * DIM / 4);
    cvt_f2b<<<(n4 + 255) / 256, 256, 0, stream>>>(x, xb, n4);
    n4 = 3 * DIM * DIM / 4;
    cvt_f2b<<<(n4 + 255) / 256, 256, 0, stream>>>(qkv_w, wb, n4);
    n4 = DIM * DIM / 4;
    cvt_f2b<<<(n4 + 255) / 256, 256, 0, stream>>>(pw, pwb, n4);
  }
  {
    dim3 g((unsigned)((Mq + 127) / 128), (unsigned)((3 * DIM) / 128));
    gemm_bf16<0><<<g, 256, 0, stream>>>(xb, wb, (int)Mq, 3 * DIM, DIM, Ntok,
                                        qb, kb, vb, nullptr, nullptr);
  }
  {
    dim3 g((unsigned)((Np + 3) / 4), 64);
    dim3 blk(96, 4);
    pool_ln<<<g, blk, 0, stream>>>(qb, pqw, nqw, nqb, qpb, qpf);
    pool_ln<<<g, blk, 0, stream>>>(kb, pkw, nkw, nkb, kpb, nullptr);
    pool_ln<<<g, blk, 0, stream>>>(vb, pvw, nvw, nvb, vpb, nullptr);
  }
  {
    dim3 g((unsigned)((Np + 63) / 64), 64);
    flash_attn<<<g, 256, 0, stream>>>(qpb, kpb, vpb, qpf, ares);
  }
  {
    dim3 g((unsigned)((Mp + 127) / 128), (unsigned)(DIM / 128));
    gemm_bf16<1><<<g, 256, 0, stream>>>(ares, pwb, (int)Mp, DIM, DIM, 0,
                                        nullptr, nullptr, nullptr, pb, (float*)d_out);
  }
}

// Round 3
// 1727.774 us; speedup vs baseline: 1.0981x; 1.0981x over previous
//
#include <hip/hip_runtime.h>
#include <hip/hip_bf16.h>

typedef short s16x8 __attribute__((ext_vector_type(8)));
typedef float f32x4 __attribute__((ext_vector_type(4)));

#define DEVI __device__ __forceinline__

DEVI unsigned short f2bf(float f) {
  unsigned u = __builtin_bit_cast(unsigned, f);
  u += 0x7FFFu + ((u >> 16) & 1u);
  return (unsigned short)(u >> 16);
}
DEVI float bf2f(unsigned short h) {
  unsigned u = ((unsigned)h) << 16;
  return __builtin_bit_cast(float, u);
}

DEVI void gload_lds16(const void* g, void* l) {
  __builtin_amdgcn_global_load_lds((const __attribute__((address_space(1))) void*)g,
                                   (__attribute__((address_space(3))) void*)l, 16, 0, 0);
}

// ---------------- fp32 -> bf16 conversion ----------------
__global__ void cvt_f2b(const float* __restrict__ src, unsigned short* __restrict__ dst, int n4) {
  int i = blockIdx.x * blockDim.x + threadIdx.x;
  if (i < n4) {
    float4 v = ((const float4*)src)[i];
    ushort4 o;
    o.x = f2bf(v.x); o.y = f2bf(v.y); o.z = f2bf(v.z); o.w = f2bf(v.w);
    ((ushort4*)dst)[i] = o;
  }
}

// ---------------- bf16 MFMA GEMM: C = A @ B^T ----------------
template <int MODE>
__global__ __launch_bounds__(256) void gemm_bf16(
    const unsigned short* __restrict__ A, const unsigned short* __restrict__ B,
    int M, int Nmat, int K, int Ntok,
    unsigned short* __restrict__ Oq, unsigned short* __restrict__ Ok, unsigned short* __restrict__ Ov,
    const float* __restrict__ bias, float* __restrict__ Cout) {
  __shared__ unsigned short As[128 * 32];
  __shared__ unsigned short Bs[128 * 32];
  const int tid = threadIdx.x;
  const int wave = tid >> 6, lane = tid & 63;
  const int tm = blockIdx.x, tn = blockIdx.y;
  const int wr = wave >> 1, wc = wave & 1;
  const int sr = lane >> 2;
  const int sc = (lane & 3) * 8;
  const int l15 = lane & 15, lg = lane >> 4;
  f32x4 acc[4][4] = {};

  for (int kt = 0; kt < K; kt += 32) {
    #pragma unroll
    for (int i = 0; i < 2; ++i) {
      int r = wave * 32 + i * 16 + sr;
      long ar = (long)tm * 128 + r; if (ar >= M) ar = M - 1;
      long br = (long)tn * 128 + r; if (br >= Nmat) br = Nmat - 1;
      gload_lds16(A + ar * K + kt + sc, &As[(wave * 32 + i * 16) * 32]);
      gload_lds16(B + br * K + kt + sc, &Bs[(wave * 32 + i * 16) * 32]);
    }
    asm volatile("s_waitcnt vmcnt(0)" ::: "memory");
    __syncthreads();
    s16x8 a[4], bfr[4];
    #pragma unroll
    for (int m = 0; m < 4; ++m)
      a[m] = *(const s16x8*)&As[(wr * 64 + m * 16 + l15) * 32 + lg * 8];
    #pragma unroll
    for (int n = 0; n < 4; ++n)
      bfr[n] = *(const s16x8*)&Bs[(wc * 64 + n * 16 + l15) * 32 + lg * 8];
    #pragma unroll
    for (int m = 0; m < 4; ++m)
      #pragma unroll
      for (int n = 0; n < 4; ++n)
        acc[m][n] = __builtin_amdgcn_mfma_f32_16x16x32_bf16(a[m], bfr[n], acc[m][n], 0, 0, 0);
    __syncthreads();
  }

  const long rbase = (long)tm * 128 + wr * 64 + lg * 4;
  const int cbase = tn * 128 + wc * 64 + l15;
  #pragma unroll
  for (int m = 0; m < 4; ++m)
    #pragma unroll
    for (int n = 0; n < 4; ++n)
      #pragma unroll
      for (int reg = 0; reg < 4; ++reg) {
        long gr = rbase + m * 16 + reg;
        int gc = cbase + n * 16;
        if (gr < M) {
          float c = acc[m][n][reg];
          if (MODE == 0) {
            int which = gc / 768; int rem = gc - which * 768;
            int head = rem / 96;  int d = rem - head * 96;
            int b = (int)(gr / Ntok); int tok = (int)(gr - (long)b * Ntok);
            unsigned short* dst = (which == 0) ? Oq : (which == 1) ? Ok : Ov;
            dst[((long)(b * 8 + head) * Ntok + tok) * 96 + d] = f2bf(c);
          } else {
            Cout[gr * (long)Nmat + gc] = c + bias[gc];
          }
        }
      }
}

// ---------------- depthwise 3x3x3 pool (stride 1,2,2) + LayerNorm ----------------
// src: (pair, 6273, 96) bf16.
// MODE 0: q -> bf16 row-major (pair,1569,96) + f32 copy
// MODE 1: k -> bf16 row-major
// MODE 2: v -> transposed (pair, d=96, key=1600), keys 1569..1599 zeroed
template <int MODE>
__global__ __launch_bounds__(256) void pool_ln2(
    const unsigned short* __restrict__ src, const float* __restrict__ cw,
    const float* __restrict__ lw, const float* __restrict__ lb,
    unsigned short* __restrict__ dst, float* __restrict__ dstf) {
  __shared__ unsigned short vt[8][96];
  const int tid = threadIdx.x;
  const int pair = blockIdx.x;
  const int slot = tid >> 5;       // 0..7 rows per block
  const int lane5 = tid & 31;
  const int p = blockIdx.y * 8 + slot;
  const bool valid = (p < 1569);

  if (MODE != 2 && !valid) return;

  float val[3] = {0.f, 0.f, 0.f};
  if (valid) {
    if (p == 0) {
      #pragma unroll
      for (int j = 0; j < 3; ++j)
        val[j] = bf2f(src[(long)pair * 6273 * 96 + lane5 + 32 * j]);
    } else {
      const int q = p - 1;
      const int tp = q / 196, rem = q - tp * 196;
      const int hp = rem / 14, wp = rem - hp * 14;
      #pragma unroll
      for (int dt = 0; dt < 3; ++dt) {
        int t = tp + dt - 1;
        if ((unsigned)t >= 8u) continue;
        #pragma unroll
        for (int dh = 0; dh < 3; ++dh) {
          int hh = hp * 2 + dh - 1;
          if ((unsigned)hh >= 28u) continue;
          #pragma unroll
          for (int dw = 0; dw < 3; ++dw) {
            int ww = wp * 2 + dw - 1;
            if ((unsigned)ww >= 28u) continue;
            const unsigned short* sp = src + ((long)pair * 6273 + 1 + (t * 28 + hh) * 28 + ww) * 96;
            const int widx = dt * 9 + dh * 3 + dw;
            #pragma unroll
            for (int j = 0; j < 3; ++j) {
              int c = lane5 + 32 * j;
              val[j] += bf2f(sp[c]) * cw[c * 27 + widx];
            }
          }
        }
      }
    }
  }
  float s1 = val[0] + val[1] + val[2];
  float s2 = val[0] * val[0] + val[1] * val[1] + val[2] * val[2];
  #pragma unroll
  for (int k = 1; k < 32; k <<= 1) {
    s1 += __shfl_xor(s1, k, 32);
    s2 += __shfl_xor(s2, k, 32);
  }
  const float mean = s1 * (1.f / 96.f);
  const float var = s2 * (1.f / 96.f) - mean * mean;
  const float rstd = rsqrtf(var + 1e-5f);
  if (MODE == 2) {
    #pragma unroll
    for (int j = 0; j < 3; ++j) {
      int c = lane5 + 32 * j;
      float nv = valid ? ((val[j] - mean) * rstd * lw[c] + lb[c]) : 0.f;
      vt[slot][c] = f2bf(nv);
    }
    __syncthreads();
    if (tid < 96) {
      s16x8 o;
      #pragma unroll
      for (int s = 0; s < 8; ++s) o[s] = (short)vt[s][tid];
      *(s16x8*)&dst[(long)pair * 153600 + (long)tid * 1600 + blockIdx.y * 8] = o;
    }
  } else {
    #pragma unroll
    for (int j = 0; j < 3; ++j) {
      int c = lane5 + 32 * j;
      float nv = (val[j] - mean) * rstd * lw[c] + lb[c];
      long off = ((long)pair * 1569 + p) * 96 + c;
      dst[off] = f2bf(nv);
      if (MODE == 0) dstf[off] = nv;
    }
  }
}

// ---------------- flash attention + residual ----------------
// Qb/Kb row-major (pair,1569,96); Vt (pair,96,1600) transposed; Qf fp32; Out (8,1569,768) bf16.
__global__ __launch_bounds__(256) void flash_attn(
    const unsigned short* __restrict__ Qb, const unsigned short* __restrict__ Kb,
    const unsigned short* __restrict__ VtG, const float* __restrict__ Qf,
    unsigned short* __restrict__ Out) {
  const int Np = 1569;
  const int pair = blockIdx.x;
  const int b = pair >> 3, h = pair & 7;
  const int tid = threadIdx.x, wave = tid >> 6, lane = tid & 63;
  const int l15 = lane & 15, lg = lane >> 4;
  const int qbase = blockIdx.y * 128 + wave * 32;

  __shared__ unsigned short Ks[32 * 104];    // [key][pitch 104]
  __shared__ unsigned short Vs[96 * 40];     // V^T tile [d][pitch 40]
  __shared__ unsigned short Ps[4 * 32 * 40]; // per-wave, chunk-swizzled

  // Q fragments: 2 m-frags x 3 kk
  s16x8 qf[2][3];
  #pragma unroll
  for (int m = 0; m < 2; ++m) {
    int qr = qbase + m * 16 + l15; if (qr >= Np) qr = Np - 1;
    const unsigned short* qp = &Qb[((long)pair * Np + qr) * 96 + lg * 8];
    qf[m][0] = *(const s16x8*)(qp);
    qf[m][1] = *(const s16x8*)(qp + 32);
    qf[m][2] = *(const s16x8*)(qp + 64);
  }

  f32x4 accO[2][6] = {};
  float mrun[2][4], lrun[2][4], sf[2][4];
  #pragma unroll
  for (int m = 0; m < 2; ++m)
    #pragma unroll
    for (int i = 0; i < 4; ++i) { mrun[m][i] = -1e30f; lrun[m][i] = 0.f; }

  const float scale = 0.1020620726159658f; // 96^-0.5
  const int NT = 50;
  const long kvbase = (long)pair * Np;
  const long vbase = (long)pair * 153600;

  for (int kt = 0; kt < NT; ++kt) {
    __syncthreads();
    // K: [32 keys][96] -> pitch 104
    for (int cc = tid; cc < 384; cc += 256) {
      int key = cc / 12, dp = (cc - key * 12) * 8;
      int gk = kt * 32 + key; if (gk >= Np) gk = Np - 1;
      s16x8 kv = *(const s16x8*)&Kb[(kvbase + gk) * 96 + dp];
      *(s16x8*)&Ks[key * 104 + dp] = kv;
    }
    // V^T: [96 d][32 keys] -> pitch 40 (cols beyond Np are pre-zeroed in VtG)
    for (int cc = tid; cc < 384; cc += 256) {
      int row = cc >> 2, coff = (cc & 3) * 8;
      s16x8 vv = *(const s16x8*)&VtG[vbase + (long)row * 1600 + kt * 32 + coff];
      *(s16x8*)&Vs[row * 40 + coff] = vv;
    }
    __syncthreads();

    // QK^T: 2 m-frags x 2 key-frags
    f32x4 s[2][2] = {};
    #pragma unroll
    for (int kk = 0; kk < 3; ++kk) {
      s16x8 b0 = *(const s16x8*)&Ks[l15 * 104 + kk * 32 + lg * 8];
      s16x8 b1 = *(const s16x8*)&Ks[(16 + l15) * 104 + kk * 32 + lg * 8];
      #pragma unroll
      for (int m = 0; m < 2; ++m) {
        s[m][0] = __builtin_amdgcn_mfma_f32_16x16x32_bf16(qf[m][kk], b0, s[m][0], 0, 0, 0);
        s[m][1] = __builtin_amdgcn_mfma_f32_16x16x32_bf16(qf[m][kk], b1, s[m][1], 0, 0, 0);
      }
    }

    const bool v0 = (kt * 32 + l15) < Np;
    const bool v1 = (kt * 32 + 16 + l15) < Np;
    #pragma unroll
    for (int m = 0; m < 2; ++m)
      #pragma unroll
      for (int i2 = 0; i2 < 4; ++i2) {
        float sm0 = v0 ? s[m][0][i2] * scale : -1e30f;
        float sm1 = v1 ? s[m][1][i2] * scale : -1e30f;
        float t = fmaxf(sm0, sm1);
        t = fmaxf(t, __shfl_xor(t, 1, 16));
        t = fmaxf(t, __shfl_xor(t, 2, 16));
        t = fmaxf(t, __shfl_xor(t, 4, 16));
        t = fmaxf(t, __shfl_xor(t, 8, 16));
        float mnew = fmaxf(mrun[m][i2], t);
        sf[m][i2] = __expf(mrun[m][i2] - mnew);
        mrun[m][i2] = mnew;
        float p0 = __expf(sm0 - mnew);
        float p1 = __expf(sm1 - mnew);
        float ps = p0 + p1;
        ps += __shfl_xor(ps, 1, 16);
        ps += __shfl_xor(ps, 2, 16);
        ps += __shfl_xor(ps, 4, 16);
        ps += __shfl_xor(ps, 8, 16);
        lrun[m][i2] = lrun[m][i2] * sf[m][i2] + ps;
        // swizzled Ps write: row = m*16+lg*4+i2; chunk' = (col>>3) ^ ((row>>2)&3) = (col>>3) ^ lg
        const int row = m * 16 + lg * 4 + i2;
        Ps[wave * 1280 + row * 40 + (((l15 >> 3) ^ lg) << 3) + (l15 & 7)] = f2bf(p0);
        Ps[wave * 1280 + row * 40 + ((((16 + l15) >> 3) ^ lg) << 3) + (l15 & 7)] = f2bf(p1);
      }
    // rescale accumulator
    #pragma unroll
    for (int m = 0; m < 2; ++m)
      #pragma unroll
      for (int db = 0; db < 6; ++db)
        #pragma unroll
        for (int i2 = 0; i2 < 4; ++i2)
          accO[m][db][i2] *= sf[m][i2];

    // P A-frags (swizzled read): row = m*16+l15, cols lg*8..+7
    s16x8 ap[2];
    #pragma unroll
    for (int m = 0; m < 2; ++m)
      ap[m] = *(const s16x8*)&Ps[wave * 1280 + (m * 16 + l15) * 40 + ((lg ^ ((l15 >> 2) & 3)) << 3)];
    // V B-frags: plain b128 from padded V^T tile
    #pragma unroll
    for (int db = 0; db < 6; ++db) {
      s16x8 bv = *(const s16x8*)&Vs[(db * 16 + l15) * 40 + lg * 8];
      accO[0][db] = __builtin_amdgcn_mfma_f32_16x16x32_bf16(ap[0], bv, accO[0][db], 0, 0, 0);
      accO[1][db] = __builtin_amdgcn_mfma_f32_16x16x32_bf16(ap[1], bv, accO[1][db], 0, 0, 0);
    }
  }

  #pragma unroll
  for (int m = 0; m < 2; ++m)
    #pragma unroll
    for (int i2 = 0; i2 < 4; ++i2) lrun[m][i2] = 1.f / lrun[m][i2];
  #pragma unroll
  for (int m = 0; m < 2; ++m) {
    const int q0 = qbase + m * 16 + lg * 4;
    #pragma unroll
    for (int db = 0; db < 6; ++db) {
      int d = db * 16 + l15;
      #pragma unroll
      for (int i2 = 0; i2 < 4; ++i2) {
        int q = q0 + i2;
        if (q < Np) {
          float o = accO[m][db][i2] * lrun[m][i2] + Qf[((long)pair * Np + q) * 96 + d];
          Out[((long)b * Np + q) * 768 + h * 96 + d] = f2bf(o);
        }
      }
    }
  }
}

extern "C" void kernel_launch(void* const* d_in, const int* in_sizes, int n_in,
                              void* d_out, int out_size, void* d_ws, size_t ws_size,
                              hipStream_t stream) {
  const float* x     = (const float*)d_in[0];
  const float* qkv_w = (const float*)d_in[1];
  const float* pqw   = (const float*)d_in[2];
  const float* pkw   = (const float*)d_in[3];
  const float* pvw   = (const float*)d_in[4];
  const float* nqw   = (const float*)d_in[5];
  const float* nqb   = (const float*)d_in[6];
  const float* nkw   = (const float*)d_in[7];
  const float* nkb   = (const float*)d_in[8];
  const float* nvw   = (const float*)d_in[9];
  const float* nvb   = (const float*)d_in[10];
  const float* pw    = (const float*)d_in[11];
  const float* pb    = (const float*)d_in[12];

  const int Ntok = 6273, DIM = 768, Np = 1569;
  const long Mq = 8L * Ntok;
  const long Mp = 8L * Np;

  char* w = (char*)d_ws;
  unsigned short* xb  = (unsigned short*)w; w += Mq * DIM * 2;
  unsigned short* wb  = (unsigned short*)w; w += 3L * DIM * DIM * 2;
  unsigned short* pwb = (unsigned short*)w; w += (long)DIM * DIM * 2;
  unsigned short* qb  = (unsigned short*)w; w += 64L * Ntok * 96 * 2;
  unsigned short* kb  = (unsigned short*)w; w += 64L * Ntok * 96 * 2;
  unsigned short* vb  = (unsigned short*)w; w += 64L * Ntok * 96 * 2;
  unsigned short* qpb = (unsigned short*)w; w += 64L * Np * 96 * 2;
  unsigned short* kpb = (unsigned short*)w; w += 64L * Np * 96 * 2;
  unsigned short* vpt = (unsigned short*)w; w += 64L * 96 * 1600 * 2;  // V^T
  float*          qpf = (float*)w;          w += 64L * Np * 96 * 4;
  unsigned short* ares= (unsigned short*)w; w += Mp * DIM * 2;

  {
    int n4 = (int)(Mq * DIM / 4);
    cvt_f2b<<<(n4 + 255) / 256, 256, 0, stream>>>(x, xb, n4);
    n4 = 3 * DIM * DIM / 4;
    cvt_f2b<<<(n4 + 255) / 256, 256, 0, stream>>>(qkv_w, wb, n4);
    n4 = DIM * DIM / 4;
    cvt_f2b<<<(n4 + 255) / 256, 256, 0, stream>>>(pw, pwb, n4);
  }
  {
    dim3 g((unsigned)((Mq + 127) / 128), (unsigned)((3 * DIM) / 128));
    gemm_bf16<0><<<g, 256, 0, stream>>>(xb, wb, (int)Mq, 3 * DIM, DIM, Ntok,
                                        qb, kb, vb, nullptr, nullptr);
  }
  {
    dim3 gq(64, (unsigned)((Np + 7) / 8));
    dim3 gv(64, 200);
    pool_ln2<0><<<gq, 256, 0, stream>>>(qb, pqw, nqw, nqb, qpb, qpf);
    pool_ln2<1><<<gq, 256, 0, stream>>>(kb, pkw, nkw, nkb, kpb, nullptr);
    pool_ln2<2><<<gv, 256, 0, stream>>>(vb, pvw, nvw, nvb, vpt, nullptr);
  }
  {
    dim3 g(64, (unsigned)((Np + 127) / 128));
    flash_attn<<<g, 256, 0, stream>>>(qpb, kpb, vpt, qpf, ares);
  }
  {
    dim3 g((unsigned)((Mp + 127) / 128), (unsigned)(DIM / 128));
    gemm_bf16<1><<<g, 256, 0, stream>>>(ares, pwb, (int)Mp, DIM, DIM, 0,
                                        nullptr, nullptr, nullptr, pb, (float*)d_out);
  }
}

// Round 5
// 1545.405 us; speedup vs baseline: 1.2276x; 1.1180x over previous
//
#include <hip/hip_runtime.h>
#include <hip/hip_bf16.h>

typedef short s16x8 __attribute__((ext_vector_type(8)));
typedef float f32x4 __attribute__((ext_vector_type(4)));

#define DEVI __device__ __forceinline__

DEVI unsigned short f2bf(float f) {
  unsigned u = __builtin_bit_cast(unsigned, f);
  u += 0x7FFFu + ((u >> 16) & 1u);
  return (unsigned short)(u >> 16);
}
DEVI float bf2f(unsigned short h) {
  unsigned u = ((unsigned)h) << 16;
  return __builtin_bit_cast(float, u);
}

DEVI void gload_lds16(const void* g, void* l) {
  __builtin_amdgcn_global_load_lds((const __attribute__((address_space(1))) void*)g,
                                   (__attribute__((address_space(3))) void*)l, 16, 0, 0);
}

// ---------------- fp32 -> bf16 conversion ----------------
__global__ void cvt_f2b(const float* __restrict__ src, unsigned short* __restrict__ dst, int n4) {
  int i = blockIdx.x * blockDim.x + threadIdx.x;
  if (i < n4) {
    float4 v = ((const float4*)src)[i];
    ushort4 o;
    o.x = f2bf(v.x); o.y = f2bf(v.y); o.z = f2bf(v.z); o.w = f2bf(v.w);
    ((ushort4*)dst)[i] = o;
  }
}

// ---------------- bf16 MFMA GEMM: C = A @ B^T ----------------
// Grid: x = tn (N tiles), y = tm (M tiles) -> consecutive blocks reuse A-panel in L2.
template <int MODE>
__global__ __launch_bounds__(256) void gemm_bf16(
    const unsigned short* __restrict__ A, const unsigned short* __restrict__ B,
    int M, int Nmat, int K, int Ntok,
    unsigned short* __restrict__ Oq, unsigned short* __restrict__ Ok, unsigned short* __restrict__ Ov,
    const float* __restrict__ bias, float* __restrict__ Cout) {
  __shared__ unsigned short As[128 * 32];
  __shared__ unsigned short Bs[128 * 32];
  const int tid = threadIdx.x;
  const int wave = tid >> 6, lane = tid & 63;
  const int tm = blockIdx.y, tn = blockIdx.x;
  const int wr = wave >> 1, wc = wave & 1;
  const int sr = lane >> 2;
  const int sc = (lane & 3) * 8;
  const int l15 = lane & 15, lg = lane >> 4;
  f32x4 acc[4][4] = {};

  for (int kt = 0; kt < K; kt += 32) {
    #pragma unroll
    for (int i = 0; i < 2; ++i) {
      int r = wave * 32 + i * 16 + sr;
      long ar = (long)tm * 128 + r; if (ar >= M) ar = M - 1;
      long br = (long)tn * 128 + r; if (br >= Nmat) br = Nmat - 1;
      gload_lds16(A + ar * K + kt + sc, &As[(wave * 32 + i * 16) * 32]);
      gload_lds16(B + br * K + kt + sc, &Bs[(wave * 32 + i * 16) * 32]);
    }
    asm volatile("s_waitcnt vmcnt(0)" ::: "memory");
    __syncthreads();
    s16x8 a[4], bfr[4];
    #pragma unroll
    for (int m = 0; m < 4; ++m)
      a[m] = *(const s16x8*)&As[(wr * 64 + m * 16 + l15) * 32 + lg * 8];
    #pragma unroll
    for (int n = 0; n < 4; ++n)
      bfr[n] = *(const s16x8*)&Bs[(wc * 64 + n * 16 + l15) * 32 + lg * 8];
    #pragma unroll
    for (int m = 0; m < 4; ++m)
      #pragma unroll
      for (int n = 0; n < 4; ++n)
        acc[m][n] = __builtin_amdgcn_mfma_f32_16x16x32_bf16(a[m], bfr[n], acc[m][n], 0, 0, 0);
    __syncthreads();
  }

  const long rbase = (long)tm * 128 + wr * 64 + lg * 4;
  const int cbase = tn * 128 + wc * 64 + l15;
  #pragma unroll
  for (int m = 0; m < 4; ++m)
    #pragma unroll
    for (int n = 0; n < 4; ++n)
      #pragma unroll
      for (int reg = 0; reg < 4; ++reg) {
        long gr = rbase + m * 16 + reg;
        int gc = cbase + n * 16;
        if (gr < M) {
          float c = acc[m][n][reg];
          if (MODE == 0) {
            int which = gc / 768; int rem = gc - which * 768;
            int head = rem / 96;  int d = rem - head * 96;
            int b = (int)(gr / Ntok); int tok = (int)(gr - (long)b * Ntok);
            unsigned short* dst = (which == 0) ? Oq : (which == 1) ? Ok : Ov;
            dst[((long)(b * 8 + head) * Ntok + tok) * 96 + d] = f2bf(c);
          } else {
            Cout[gr * (long)Nmat + gc] = c + bias[gc];
          }
        }
      }
}

// ---------------- depthwise 3x3x3 pool (stride 1,2,2) + LayerNorm ----------------
// src: (pair, 6273, 96) bf16.
// MODE 0: q -> bf16 row-major (pair,1569,96) + f32 copy
// MODE 1: k -> bf16 row-major
// MODE 2: v -> transposed (pair, d=96, key=1600), keys 1569..1599 zeroed
template <int MODE>
__global__ __launch_bounds__(256) void pool_ln2(
    const unsigned short* __restrict__ src, const float* __restrict__ cw,
    const float* __restrict__ lw, const float* __restrict__ lb,
    unsigned short* __restrict__ dst, float* __restrict__ dstf) {
  __shared__ unsigned short vt[8][96];
  const int tid = threadIdx.x;
  const int pair = blockIdx.x;
  const int slot = tid >> 5;       // 0..7 rows per block
  const int lane5 = tid & 31;
  const int p = blockIdx.y * 8 + slot;
  const bool valid = (p < 1569);

  if (MODE != 2 && !valid) return;

  float val[3] = {0.f, 0.f, 0.f};
  if (valid) {
    if (p == 0) {
      #pragma unroll
      for (int j = 0; j < 3; ++j)
        val[j] = bf2f(src[(long)pair * 6273 * 96 + lane5 + 32 * j]);
    } else {
      const int q = p - 1;
      const int tp = q / 196, rem = q - tp * 196;
      const int hp = rem / 14, wp = rem - hp * 14;
      #pragma unroll
      for (int dt = 0; dt < 3; ++dt) {
        int t = tp + dt - 1;
        if ((unsigned)t >= 8u) continue;
        #pragma unroll
        for (int dh = 0; dh < 3; ++dh) {
          int hh = hp * 2 + dh - 1;
          if ((unsigned)hh >= 28u) continue;
          #pragma unroll
          for (int dw = 0; dw < 3; ++dw) {
            int ww = wp * 2 + dw - 1;
            if ((unsigned)ww >= 28u) continue;
            const unsigned short* sp = src + ((long)pair * 6273 + 1 + (t * 28 + hh) * 28 + ww) * 96;
            const int widx = dt * 9 + dh * 3 + dw;
            #pragma unroll
            for (int j = 0; j < 3; ++j) {
              int c = lane5 + 32 * j;
              val[j] += bf2f(sp[c]) * cw[c * 27 + widx];
            }
          }
        }
      }
    }
  }
  float s1 = val[0] + val[1] + val[2];
  float s2 = val[0] * val[0] + val[1] * val[1] + val[2] * val[2];
  #pragma unroll
  for (int k = 1; k < 32; k <<= 1) {
    s1 += __shfl_xor(s1, k, 32);
    s2 += __shfl_xor(s2, k, 32);
  }
  const float mean = s1 * (1.f / 96.f);
  const float var = s2 * (1.f / 96.f) - mean * mean;
  const float rstd = rsqrtf(var + 1e-5f);
  if (MODE == 2) {
    #pragma unroll
    for (int j = 0; j < 3; ++j) {
      int c = lane5 + 32 * j;
      float nv = valid ? ((val[j] - mean) * rstd * lw[c] + lb[c]) : 0.f;
      vt[slot][c] = f2bf(nv);
    }
    __syncthreads();
    if (tid < 96) {
      s16x8 o;
      #pragma unroll
      for (int s = 0; s < 8; ++s) o[s] = (short)vt[s][tid];
      *(s16x8*)&dst[(long)pair * 153600 + (long)tid * 1600 + blockIdx.y * 8] = o;
    }
  } else {
    #pragma unroll
    for (int j = 0; j < 3; ++j) {
      int c = lane5 + 32 * j;
      float nv = (val[j] - mean) * rstd * lw[c] + lb[c];
      long off = ((long)pair * 1569 + p) * 96 + c;
      dst[off] = f2bf(nv);
      if (MODE == 0) dstf[off] = nv;
    }
  }
}

// ---------------- flash attention (unnormalized-exp) + residual ----------------
// Qb/Kb row-major (pair,1569,96); Vt (pair,96,1600) transposed; Qf fp32; Out (8,1569,768) bf16.
DEVI void pref_kv(const unsigned short* __restrict__ Kb, const unsigned short* __restrict__ VtG,
                  long kvbase, long vbase, int kt, int tid, int Np,
                  s16x8 kpre[2], s16x8 vpre[2]) {
  #pragma unroll
  for (int u = 0; u < 2; ++u) {
    int cc = tid + u * 256;
    if (cc < 384) {
      int key = cc / 12, dp = (cc - key * 12) * 8;
      int gk = kt * 32 + key; if (gk >= Np) gk = Np - 1;
      kpre[u] = *(const s16x8*)&Kb[(kvbase + gk) * 96 + dp];
      int row = cc >> 2, coff = (cc & 3) * 8;
      vpre[u] = *(const s16x8*)&VtG[vbase + (long)row * 1600 + kt * 32 + coff];
    }
  }
}

__global__ __launch_bounds__(256) void flash_attn(
    const unsigned short* __restrict__ Qb, const unsigned short* __restrict__ Kb,
    const unsigned short* __restrict__ VtG, const float* __restrict__ Qf,
    unsigned short* __restrict__ Out) {
  const int Np = 1569;
  const int pair = blockIdx.x;
  const int b = pair >> 3, h = pair & 7;
  const int tid = threadIdx.x, wave = tid >> 6, lane = tid & 63;
  const int l15 = lane & 15, lg = lane >> 4;
  const int qbase = blockIdx.y * 128 + wave * 32;

  __shared__ unsigned short Ks[32 * 104];    // [key][pitch 104]
  __shared__ unsigned short Vs[96 * 40];     // V^T tile [d][pitch 40]
  __shared__ unsigned short Ps[4 * 32 * 40]; // per-wave, chunk-swizzled

  // Q fragments: 2 m-frags x 3 kk
  s16x8 qf[2][3];
  #pragma unroll
  for (int m = 0; m < 2; ++m) {
    int qr = qbase + m * 16 + l15; if (qr >= Np) qr = Np - 1;
    const unsigned short* qp = &Qb[((long)pair * Np + qr) * 96 + lg * 8];
    qf[m][0] = *(const s16x8*)(qp);
    qf[m][1] = *(const s16x8*)(qp + 32);
    qf[m][2] = *(const s16x8*)(qp + 64);
  }

  f32x4 accO[2][6] = {};
  float lsum[2][4] = {};

  const float scale = 0.1020620726159658f; // 96^-0.5
  const int NT = 50;
  const long kvbase = (long)pair * Np;
  const long vbase = (long)pair * 153600;

  s16x8 kpre[2], vpre[2];
  pref_kv(Kb, VtG, kvbase, vbase, 0, tid, Np, kpre, vpre);

  for (int kt = 0; kt < NT; ++kt) {
    __syncthreads();
    // write prefetched tile to LDS
    #pragma unroll
    for (int u = 0; u < 2; ++u) {
      int cc = tid + u * 256;
      if (cc < 384) {
        int key = cc / 12, dp = (cc - key * 12) * 8;
        *(s16x8*)&Ks[key * 104 + dp] = kpre[u];
        int row = cc >> 2, coff = (cc & 3) * 8;
        *(s16x8*)&Vs[row * 40 + coff] = vpre[u];
      }
    }
    __syncthreads();
    // issue next tile's loads (latency hides under compute)
    if (kt + 1 < NT)
      pref_kv(Kb, VtG, kvbase, vbase, kt + 1, tid, Np, kpre, vpre);

    // QK^T: 2 m-frags x 2 key-frags
    f32x4 s[2][2] = {};
    #pragma unroll
    for (int kk = 0; kk < 3; ++kk) {
      s16x8 b0 = *(const s16x8*)&Ks[l15 * 104 + kk * 32 + lg * 8];
      s16x8 b1 = *(const s16x8*)&Ks[(16 + l15) * 104 + kk * 32 + lg * 8];
      #pragma unroll
      for (int m = 0; m < 2; ++m) {
        s[m][0] = __builtin_amdgcn_mfma_f32_16x16x32_bf16(qf[m][kk], b0, s[m][0], 0, 0, 0);
        s[m][1] = __builtin_amdgcn_mfma_f32_16x16x32_bf16(qf[m][kk], b1, s[m][1], 0, 0, 0);
      }
    }

    const bool v0 = (kt * 32 + l15) < Np;
    const bool v1 = (kt * 32 + 16 + l15) < Np;
    #pragma unroll
    for (int m = 0; m < 2; ++m)
      #pragma unroll
      for (int i2 = 0; i2 < 4; ++i2) {
        float p0 = v0 ? __expf(fminf(s[m][0][i2] * scale, 30.f)) : 0.f;
        float p1 = v1 ? __expf(fminf(s[m][1][i2] * scale, 30.f)) : 0.f;
        lsum[m][i2] += p0 + p1;
        // swizzled Ps write: row = m*16+lg*4+i2; chunk' = (col>>3) ^ lg
        const int row = m * 16 + lg * 4 + i2;
        Ps[wave * 1280 + row * 40 + (((l15 >> 3) ^ lg) << 3) + (l15 & 7)] = f2bf(p0);
        Ps[wave * 1280 + row * 40 + ((((16 + l15) >> 3) ^ lg) << 3) + (l15 & 7)] = f2bf(p1);
      }

    // P A-frags (swizzled read): row = m*16+l15, cols lg*8..+7
    s16x8 ap[2];
    #pragma unroll
    for (int m = 0; m < 2; ++m)
      ap[m] = *(const s16x8*)&Ps[wave * 1280 + (m * 16 + l15) * 40 + ((lg ^ ((l15 >> 2) & 3)) << 3)];
    // V B-frags: plain b128 from padded V^T tile
    #pragma unroll
    for (int db = 0; db < 6; ++db) {
      s16x8 bv = *(const s16x8*)&Vs[(db * 16 + l15) * 40 + lg * 8];
      accO[0][db] = __builtin_amdgcn_mfma_f32_16x16x32_bf16(ap[0], bv, accO[0][db], 0, 0, 0);
      accO[1][db] = __builtin_amdgcn_mfma_f32_16x16x32_bf16(ap[1], bv, accO[1][db], 0, 0, 0);
    }
  }

  // one-time cross-lane sum reduce (keys live across the 16-lane group)
  float linv[2][4];
  #pragma unroll
  for (int m = 0; m < 2; ++m)
    #pragma unroll
    for (int i2 = 0; i2 < 4; ++i2) {
      float t = lsum[m][i2];
      t += __shfl_xor(t, 1, 16);
      t += __shfl_xor(t, 2, 16);
      t += __shfl_xor(t, 4, 16);
      t += __shfl_xor(t, 8, 16);
      linv[m][i2] = 1.f / t;
    }

  #pragma unroll
  for (int m = 0; m < 2; ++m) {
    const int q0 = qbase + m * 16 + lg * 4;
    #pragma unroll
    for (int db = 0; db < 6; ++db) {
      int d = db * 16 + l15;
      #pragma unroll
      for (int i2 = 0; i2 < 4; ++i2) {
        int q = q0 + i2;
        if (q < Np) {
          float o = accO[m][db][i2] * linv[m][i2] + Qf[((long)pair * Np + q) * 96 + d];
          Out[((long)b * Np + q) * 768 + h * 96 + d] = f2bf(o);
        }
      }
    }
  }
}

extern "C" void kernel_launch(void* const* d_in, const int* in_sizes, int n_in,
                              void* d_out, int out_size, void* d_ws, size_t ws_size,
                              hipStream_t stream) {
  const float* x     = (const float*)d_in[0];
  const float* qkv_w = (const float*)d_in[1];
  const float* pqw   = (const float*)d_in[2];
  const float* pkw   = (const float*)d_in[3];
  const float* pvw   = (const float*)d_in[4];
  const float* nqw   = (const float*)d_in[5];
  const float* nqb   = (const float*)d_in[6];
  const float* nkw   = (const float*)d_in[7];
  const float* nkb   = (const float*)d_in[8];
  const float* nvw   = (const float*)d_in[9];
  const float* nvb   = (const float*)d_in[10];
  const float* pw    = (const float*)d_in[11];
  const float* pb    = (const float*)d_in[12];

  const int Ntok = 6273, DIM = 768, Np = 1569;
  const long Mq = 8L * Ntok;
  const long Mp = 8L * Np;

  char* w = (char*)d_ws;
  unsigned short* xb  = (unsigned short*)w; w += Mq * DIM * 2;
  unsigned short* wb  = (unsigned short*)w; w += 3L * DIM * DIM * 2;
  unsigned short* pwb = (unsigned short*)w; w += (long)DIM * DIM * 2;
  unsigned short* qb  = (unsigned short*)w; w += 64L * Ntok * 96 * 2;
  unsigned short* kb  = (unsigned short*)w; w += 64L * Ntok * 96 * 2;
  unsigned short* vb  = (unsigned short*)w; w += 64L * Ntok * 96 * 2;
  unsigned short* qpb = (unsigned short*)w; w += 64L * Np * 96 * 2;
  unsigned short* kpb = (unsigned short*)w; w += 64L * Np * 96 * 2;
  unsigned short* vpt = (unsigned short*)w; w += 64L * 96 * 1600 * 2;  // V^T
  float*          qpf = (float*)w;          w += 64L * Np * 96 * 4;
  unsigned short* ares= (unsigned short*)w; w += Mp * DIM * 2;

  {
    int n4 = (int)(Mq * DIM / 4);
    cvt_f2b<<<(n4 + 255) / 256, 256, 0, stream>>>(x, xb, n4);
    n4 = 3 * DIM * DIM / 4;
    cvt_f2b<<<(n4 + 255) / 256, 256, 0, stream>>>(qkv_w, wb, n4);
    n4 = DIM * DIM / 4;
    cvt_f2b<<<(n4 + 255) / 256, 256, 0, stream>>>(pw, pwb, n4);
  }
  {
    dim3 g((unsigned)((3 * DIM) / 128), (unsigned)((Mq + 127) / 128));
    gemm_bf16<0><<<g, 256, 0, stream>>>(xb, wb, (int)Mq, 3 * DIM, DIM, Ntok,
                                        qb, kb, vb, nullptr, nullptr);
  }
  {
    dim3 gq(64, (unsigned)((Np + 7) / 8));
    dim3 gv(64, 200);
    pool_ln2<0><<<gq, 256, 0, stream>>>(qb, pqw, nqw, nqb, qpb, qpf);
    pool_ln2<1><<<gq, 256, 0, stream>>>(kb, pkw, nkw, nkb, kpb, nullptr);
    pool_ln2<2><<<gv, 256, 0, stream>>>(vb, pvw, nvw, nvb, vpt, nullptr);
  }
  {
    dim3 g(64, (unsigned)((Np + 127) / 128));
    flash_attn<<<g, 256, 0, stream>>>(qpb, kpb, vpt, qpf, ares);
  }
  {
    dim3 g((unsigned)(DIM / 128), (unsigned)((Mp + 127) / 128));
    gemm_bf16<1><<<g, 256, 0, stream>>>(ares, pwb, (int)Mp, DIM, DIM, 0,
                                        nullptr, nullptr, nullptr, pb, (float*)d_out);
  }
}